// Round 3
// baseline (751.653 us; speedup 1.0000x reference)
//
#include <hip/hip_runtime.h>

typedef unsigned short u16;
typedef __attribute__((ext_vector_type(4))) float f32x4;
typedef __attribute__((ext_vector_type(8))) short bf16x8;
typedef __attribute__((ext_vector_type(8))) unsigned short u16x8;
typedef __attribute__((ext_vector_type(4))) unsigned short u16x4;

__device__ __forceinline__ u16 f2bf(float f) {
  union { float f; unsigned u; } v; v.f = f;
  unsigned r = v.u + 0x7FFFu + ((v.u >> 16) & 1u);
  return (u16)(r >> 16);
}
__device__ __forceinline__ float bf2f(u16 h) {
  union { unsigned u; float f; } v; v.u = ((unsigned)h) << 16; return v.f;
}

__device__ __forceinline__ void gload_lds16(const void* g, void* l) {
  __builtin_amdgcn_global_load_lds((const __attribute__((address_space(1))) void*)g,
                                   (__attribute__((address_space(3))) void*)l, 16, 0, 0);
}

// ---------------- prep kernels ----------------

__global__ void k_zero(u16x8* __restrict__ p, int n8) {
  int i = blockIdx.x * blockDim.x + threadIdx.x;
  int stride = gridDim.x * blockDim.x;
  u16x8 z = (u16x8)0;
  for (; i < n8; i += stride) p[i] = z;
}

__global__ void k_cvt_x(const float* __restrict__ in, u16* __restrict__ out, int n4) {
  int i = blockIdx.x * blockDim.x + threadIdx.x;
  int stride = gridDim.x * blockDim.x;
  const f32x4* in4 = (const f32x4*)in;
  u16x4* out4 = (u16x4*)out;
  for (; i < n4; i += stride) {
    f32x4 v = in4[i];
    u16x4 o;
    o[0] = f2bf(v[0]); o[1] = f2bf(v[1]); o[2] = f2bf(v[2]); o[3] = f2bf(v[3]);
    out4[i] = o;
  }
}

// w [K][N] f32 -> outT [N][K] bf16 (plain transpose)
__global__ void k_wt(const float* __restrict__ w, u16* __restrict__ outT, int K, int N) {
  int i = blockIdx.x * blockDim.x + threadIdx.x;
  int total = K * N;
  int stride = gridDim.x * blockDim.x;
  for (; i < total; i += stride) {
    int k = i / N, n = i - k * N;
    outT[(size_t)n * K + k] = f2bf(w[i]);
  }
}

// w [K][N] f32 -> outT [N][2K] bf16: rows n, cols 0..K-1 = hi, K..2K-1 = lo
__global__ void k_split_w(const float* __restrict__ w, u16* __restrict__ outT, int K, int N) {
  int i = blockIdx.x * blockDim.x + threadIdx.x;
  int total = K * N;
  int stride = gridDim.x * blockDim.x;
  for (; i < total; i += stride) {
    int k = i / N, n = i - k * N;
    float f = w[i];
    u16 hi = f2bf(f);
    u16 lo = f2bf(f - bf2f(hi));
    size_t o = (size_t)n * (2 * K) + k;
    outT[o] = hi;
    outT[o + K] = lo;
  }
}

// y [1232][768] f32 -> yb [1232][1536] bf16 (columns duplicated)
__global__ void k_prep_y(const float* __restrict__ y, u16* __restrict__ yb) {
  int i = blockIdx.x * blockDim.x + threadIdx.x;
  int total = 1232 * 1536;
  int stride = gridDim.x * blockDim.x;
  for (; i < total; i += stride) {
    int m = i / 1536, k = i - m * 1536;
    int ks = (k < 768) ? k : k - 768;
    yb[i] = f2bf(y[m * 768 + ks]);
  }
}

// ---------------- small GEMM (K/V projections), m97-style 128^2 ----------------
// C[m,n] = sum_k A[m,k] * B[n][k]
// EPI 2: +bias, bf16 -> KT[b][h][96 s][64 d] (K, natural, m=b*77+s, n=h*64+d)
// EPI 3: +bias, bf16 -> VT[b][h][64 d][96 s] (V, transposed)
template <int EPI>
__global__ __launch_bounds__(256, 2) void gemm_bf16(
    const u16* __restrict__ A, const u16* __restrict__ B,
    const float* __restrict__ bias, void* __restrict__ outp,
    int M, int Kdim)
{
  __shared__ u16 sA[128 * 32];
  __shared__ u16 sB[128 * 32];
  const int t = threadIdx.x;
  const int ntiles = 8; // N = 1024
  const int bm = blockIdx.x / ntiles, bn = blockIdx.x % ntiles;
  const int m0 = bm * 128, n0 = bn * 128;
  const int l = t & 63, wv_ = t >> 6;
  const int lr = l & 15, lg = l >> 4;
  const int wm = (wv_ >> 1) * 64, wn = (wv_ & 1) * 64;

  const int srow = t >> 2;
  const int ssw = ((t >> 2) & 3) ^ ((t >> 4) & 3);
  const int scol = ((t & 3) ^ ssw) * 8;
  char* ldsA = (char*)sA;
  char* ldsB = (char*)sB;
  const int ldsoff = wv_ * 1024;

  const int swl = (lr & 3) ^ ((lr >> 2) & 3);
  const int rds = (lg ^ swl) * 8;

  f32x4 acc[4][4] = {};

  const int kiter = Kdim / 32;
  for (int kt = 0; kt < kiter; ++kt) {
    const int k0 = kt * 32;
    __syncthreads();
    {
      int r1 = m0 + srow;       if (r1 > M - 1) r1 = M - 1;
      int r2 = m0 + 64 + srow;  if (r2 > M - 1) r2 = M - 1;
      gload_lds16(A + (size_t)r1 * Kdim + k0 + scol, ldsA + 0    + ldsoff);
      gload_lds16(A + (size_t)r2 * Kdim + k0 + scol, ldsA + 4096 + ldsoff);
      gload_lds16(B + (size_t)(n0 + srow) * Kdim + k0 + scol,      ldsB + 0    + ldsoff);
      gload_lds16(B + (size_t)(n0 + 64 + srow) * Kdim + k0 + scol, ldsB + 4096 + ldsoff);
    }
    __syncthreads();
    bf16x8 af[4], bfr[4];
#pragma unroll
    for (int mt = 0; mt < 4; ++mt)
      af[mt] = *(const bf16x8*)&sA[(wm + mt * 16 + lr) * 32 + rds];
#pragma unroll
    for (int nt = 0; nt < 4; ++nt)
      bfr[nt] = *(const bf16x8*)&sB[(wn + nt * 16 + lr) * 32 + rds];
#pragma unroll
    for (int mt = 0; mt < 4; ++mt)
#pragma unroll
      for (int nt = 0; nt < 4; ++nt)
        acc[mt][nt] = __builtin_amdgcn_mfma_f32_16x16x32_bf16(af[mt], bfr[nt], acc[mt][nt], 0, 0, 0);
  }

#pragma unroll
  for (int mt = 0; mt < 4; ++mt) {
#pragma unroll
    for (int nt = 0; nt < 4; ++nt) {
      const int gc = n0 + wn + nt * 16 + lr;
      const float bb = bias[gc];
#pragma unroll
      for (int r = 0; r < 4; ++r) {
        const int gr = m0 + wm + mt * 16 + lg * 4 + r;
        const float v = acc[mt][nt][r] + bb;
        if constexpr (EPI == 2) {
          if (gr < M) {
            int bb2 = gr / 77, s = gr - bb2 * 77;
            int hh = gc >> 6, d = gc & 63;
            ((u16*)outp)[(((size_t)bb2 * 16 + hh) * 96 + s) * 64 + d] = f2bf(v);
          }
        } else {
          if (gr < M) {
            int bb2 = gr / 77, s = gr - bb2 * 77;
            int hh = gc >> 6, d = gc & 63;
            ((u16*)outp)[(((size_t)bb2 * 16 + hh) * 64 + d) * 96 + s] = f2bf(v);
          }
        }
      }
    }
  }
}

// ---------------- big GEMM: 256x256 tile, deep pipeline ----------------
// M = 65536, N = 1024, K = 1024 fixed. A row-major [M][1024] bf16,
// B pre-transposed [1024 n][1024 k] bf16.
// A: 4-slot LDS ring (32KB/slot), staged 3 K-tiles ahead via global_load_lds.
// B: global->registers, 1 K-tile ahead (L2-resident 2MB weight panel).
// Per K-tile: 4 phases {4x ds_read_b128 (XOR-swz) ; 16 MFMA ; s_barrier}.
// One counted s_waitcnt vmcnt(12) per K-tile boundary -- never drains to 0.
// EPI 0: +bias -> bf16, EPI 1: +bias -> f32.
template <int EPI>
__global__ __launch_bounds__(512, 2) void gemm256(
    const u16* __restrict__ A, const u16* __restrict__ B,
    const float* __restrict__ bias, void* __restrict__ outp)
{
  __shared__ char sAraw[131072];  // 4 slots x (256 rows x 64 k x 2B)
  const int t = threadIdx.x;
  const int cpx = (int)gridDim.x >> 3;
  const int swz = ((int)blockIdx.x & 7) * cpx + ((int)blockIdx.x >> 3);
  const int bm = swz >> 2, bn = swz & 3;
  const int m0 = bm * 256, n0 = bn * 256;
  const int w = t >> 6, l = t & 63, lr = l & 15, lg = l >> 4;
  const int wm = w >> 2, wn = w & 3;  // 2 M-waves x 4 N-waves

  // staging geometry: linear 16B slot s = ii*512 + t; row = s>>3; phys slot = t&7
  const int base_r = t >> 3;
  const int cs = ((t & 7) ^ (base_r & 7)) << 3;   // inverse-swizzled global k-offset (elems)
  // read-side swizzled byte offsets (r&7 == lr&7 for all our frag rows)
  const int sw0 = ((lg ^ (lr & 7)) << 4);
  const int sw1 = (((4 + lg) ^ (lr & 7)) << 4);
  const int rrow = wm * 128 + lr;

  f32x4 acc[8][4] = {};
  bf16x8 Ba[8], Bb[8];  // [kk*4 + nt], double-buffered across tiles

  const u16* bp = B + (size_t)(n0 + wn * 64 + lr) * 1024 + lg * 8;

#define LOADB_(ktl, BD) { \
  const u16* bq = bp + (ktl) * 64; \
  _Pragma("unroll") for (int nt = 0; nt < 4; ++nt) { \
    BD[nt]     = *(const bf16x8*)(bq + (size_t)nt * 16384); \
    BD[4 + nt] = *(const bf16x8*)(bq + (size_t)nt * 16384 + 32); \
  } }

#define STAGEA_(kts, slot) { \
  _Pragma("unroll") for (int ii = 0; ii < 4; ++ii) \
    gload_lds16(A + (size_t)(m0 + ii * 64 + base_r) * 1024 + (kts) * 64 + cs, \
                sAraw + (slot) * 32768 + ii * 8192 + w * 1024); }

#define RDMFMA_(mh, kk, BC) { \
  bf16x8 a_[4]; \
  _Pragma("unroll") for (int q = 0; q < 4; ++q) \
    a_[q] = *(const bf16x8*)(sAraw + slotbase + ((rrow + (mh) * 64 + q * 16) << 7) + ((kk) ? sw1 : sw0)); \
  __builtin_amdgcn_s_setprio(1); \
  _Pragma("unroll") for (int q = 0; q < 4; ++q) \
    _Pragma("unroll") for (int nt = 0; nt < 4; ++nt) \
      acc[(mh) * 4 + q][nt] = __builtin_amdgcn_mfma_f32_16x16x32_bf16(a_[q], BC[(kk) * 4 + nt], acc[(mh) * 4 + q][nt], 0, 0, 0); \
  __builtin_amdgcn_s_setprio(0); }

#define TILE_(tcur, BC, BN_) { \
  const int slotbase = ((tcur) & 3) * 32768; \
  { /* phase 0: reads + next-B + stage(t+3) + MFMA quadrant */ \
    int ktl = (tcur) + 1; if (ktl > 15) ktl = 15; \
    int kts = (tcur) + 3; if (kts > 15) kts = 15; \
    bf16x8 a_[4]; \
    _Pragma("unroll") for (int q = 0; q < 4; ++q) \
      a_[q] = *(const bf16x8*)(sAraw + slotbase + ((rrow + q * 16) << 7) + sw0); \
    LOADB_(ktl, BN_); \
    STAGEA_(kts, ((tcur) + 3) & 3); \
    __builtin_amdgcn_s_setprio(1); \
    _Pragma("unroll") for (int q = 0; q < 4; ++q) \
      _Pragma("unroll") for (int nt = 0; nt < 4; ++nt) \
        acc[q][nt] = __builtin_amdgcn_mfma_f32_16x16x32_bf16(a_[q], BC[nt], acc[q][nt], 0, 0, 0); \
    __builtin_amdgcn_s_setprio(0); \
    __builtin_amdgcn_s_barrier(); \
  } \
  { /* phase 1 */ RDMFMA_(1, 0, BC); __builtin_amdgcn_s_barrier(); } \
  { /* phase 2 */ RDMFMA_(0, 1, BC); __builtin_amdgcn_s_barrier(); } \
  { /* phase 3 + counted boundary wait (never 0) */ \
    RDMFMA_(1, 1, BC); \
    asm volatile("s_waitcnt vmcnt(12)" ::: "memory"); \
    __builtin_amdgcn_sched_barrier(0); \
    __builtin_amdgcn_s_barrier(); } }

  // prologue: stage tiles 0,1,2 ; load B(0)
  STAGEA_(0, 0);
  STAGEA_(1, 1);
  STAGEA_(2, 2);
  LOADB_(0, Ba);
  asm volatile("s_waitcnt vmcnt(16)" ::: "memory");  // A(0) landed; A(1),A(2),B(0) may fly
  __builtin_amdgcn_sched_barrier(0);
  __builtin_amdgcn_s_barrier();

#pragma unroll 1
  for (int i = 0; i < 8; ++i) {
    TILE_(2 * i,     Ba, Bb);
    TILE_(2 * i + 1, Bb, Ba);
  }
  asm volatile("s_waitcnt vmcnt(0)" ::: "memory");  // drain dummy stages before endpgm
  __builtin_amdgcn_sched_barrier(0);

#undef LOADB_
#undef STAGEA_
#undef RDMFMA_
#undef TILE_

  // epilogue: C row = m0 + wm*128 + mt*16 + lg*4 + r ; col = n0 + wn*64 + nt*16 + lr
#pragma unroll
  for (int mt = 0; mt < 8; ++mt) {
#pragma unroll
    for (int nt = 0; nt < 4; ++nt) {
      const int gc = n0 + wn * 64 + nt * 16 + lr;
      const float bb = bias[gc];
#pragma unroll
      for (int r = 0; r < 4; ++r) {
        const int gr = m0 + wm * 128 + mt * 16 + lg * 4 + r;
        const float v = acc[mt][nt][r] + bb;
        if constexpr (EPI == 0) {
          ((u16*)outp)[(size_t)gr * 1024 + gc] = f2bf(v);
        } else {
          ((float*)outp)[(size_t)gr * 1024 + gc] = v;
        }
      }
    }
  }
}

// ---------------- fused attention ----------------
// KT [B][H][96 s][64 d] bf16 (rows>=77 zero), VT [B][H][64 d][96 s] bf16 (cols>=77 zero)
// QB [65536][1024] bf16: read q, write attn-out in place (same rows/cols per block).
__global__ __launch_bounds__(256) void k_attn(const u16* __restrict__ KT,
                                              const u16* __restrict__ VT,
                                              u16* __restrict__ QB)
{
  __shared__ u16 sK[96 * 72];
  __shared__ u16 sV[64 * 104];
  __shared__ u16 sP[4][32 * 104];

  const int bid = blockIdx.x;
  const int h = bid & 15, b = (bid >> 4) & 15, blk = bid >> 8;
  const int t = threadIdx.x;

  const u16* gK = KT + (size_t)(b * 16 + h) * (96 * 64);
  const u16* gV = VT + (size_t)(b * 16 + h) * (64 * 96);
#pragma unroll
  for (int c = 0; c < 3; ++c) {
    int e = t * 8 + c * 2048;
    { int row = e >> 6, col = e & 63;
      *(u16x8*)&sK[row * 72 + col] = *(const u16x8*)&gK[e]; }
    { int row = e / 96, col = e - (e / 96) * 96;
      *(u16x8*)&sV[row * 104 + col] = *(const u16x8*)&gV[e]; }
  }
  __syncthreads();

  const int l = t & 63, w = t >> 6, lr = l & 15, lg = l >> 4;
  const size_t rowbase = (size_t)b * 4096 + blk * 128 + w * 32;

  bf16x8 aq[2][2];
#pragma unroll
  for (int mt = 0; mt < 2; ++mt)
#pragma unroll
    for (int ks = 0; ks < 2; ++ks)
      aq[mt][ks] = *(const bf16x8*)&QB[(rowbase + mt * 16 + lr) * 1024 + h * 64 + ks * 32 + lg * 8];

  f32x4 s_[2][5] = {};
#pragma unroll
  for (int nt = 0; nt < 5; ++nt) {
#pragma unroll
    for (int ks = 0; ks < 2; ++ks) {
      bf16x8 bk = *(const bf16x8*)&sK[(nt * 16 + lr) * 72 + ks * 32 + lg * 8];
#pragma unroll
      for (int mt = 0; mt < 2; ++mt)
        s_[mt][nt] = __builtin_amdgcn_mfma_f32_16x16x32_bf16(aq[mt][ks], bk, s_[mt][nt], 0, 0, 0);
    }
  }
#pragma unroll
  for (int mt = 0; mt < 2; ++mt)
#pragma unroll
    for (int nt = 0; nt < 5; ++nt)
#pragma unroll
      for (int r = 0; r < 4; ++r)
        s_[mt][nt][r] *= 0.125f;
  if (lr >= 13) {
#pragma unroll
    for (int mt = 0; mt < 2; ++mt)
#pragma unroll
      for (int r = 0; r < 4; ++r)
        s_[mt][4][r] = -1e30f;
  }

  float ri[2][4];
#pragma unroll
  for (int mt = 0; mt < 2; ++mt) {
#pragma unroll
    for (int r = 0; r < 4; ++r) {
      float m1 = s_[mt][0][r];
#pragma unroll
      for (int nt = 1; nt < 5; ++nt) m1 = fmaxf(m1, s_[mt][nt][r]);
      m1 = fmaxf(m1, __shfl_xor(m1, 1, 64));
      m1 = fmaxf(m1, __shfl_xor(m1, 2, 64));
      m1 = fmaxf(m1, __shfl_xor(m1, 4, 64));
      m1 = fmaxf(m1, __shfl_xor(m1, 8, 64));
      float s1 = 0.f;
#pragma unroll
      for (int nt = 0; nt < 5; ++nt) {
        float e = __expf(s_[mt][nt][r] - m1);
        s_[mt][nt][r] = e;
        s1 += e;
      }
      s1 += __shfl_xor(s1, 1, 64);
      s1 += __shfl_xor(s1, 2, 64);
      s1 += __shfl_xor(s1, 4, 64);
      s1 += __shfl_xor(s1, 8, 64);
      ri[mt][r] = 1.0f / s1;
    }
  }

#pragma unroll
  for (int mt = 0; mt < 2; ++mt)
#pragma unroll
    for (int nt = 0; nt < 5; ++nt)
#pragma unroll
      for (int r = 0; r < 4; ++r)
        sP[w][(mt * 16 + lg * 4 + r) * 104 + nt * 16 + lr] = f2bf(s_[mt][nt][r] * ri[mt][r]);
#pragma unroll
  for (int mt = 0; mt < 2; ++mt)
#pragma unroll
    for (int r = 0; r < 4; ++r)
      sP[w][(mt * 16 + lg * 4 + r) * 104 + 80 + lr] = 0;

  f32x4 o_[2][4] = {};
#pragma unroll
  for (int ks = 0; ks < 3; ++ks) {
    bf16x8 ap[2];
#pragma unroll
    for (int mt = 0; mt < 2; ++mt)
      ap[mt] = *(const bf16x8*)&sP[w][(mt * 16 + lr) * 104 + ks * 32 + lg * 8];
#pragma unroll
    for (int nt = 0; nt < 4; ++nt) {
      bf16x8 bv = *(const bf16x8*)&sV[(nt * 16 + lr) * 104 + ks * 32 + lg * 8];
#pragma unroll
      for (int mt = 0; mt < 2; ++mt)
        o_[mt][nt] = __builtin_amdgcn_mfma_f32_16x16x32_bf16(ap[mt], bv, o_[mt][nt], 0, 0, 0);
    }
  }

#pragma unroll
  for (int mt = 0; mt < 2; ++mt)
#pragma unroll
    for (int nt = 0; nt < 4; ++nt)
#pragma unroll
      for (int r = 0; r < 4; ++r)
        QB[(rowbase + mt * 16 + lg * 4 + r) * 1024 + h * 64 + nt * 16 + lr] = f2bf(o_[mt][nt][r]);
}

// ---------------- launch ----------------

extern "C" void kernel_launch(void* const* d_in, const int* in_sizes, int n_in,
                              void* d_out, int out_size, void* d_ws, size_t ws_size,
                              hipStream_t stream) {
  const float* x  = (const float*)d_in[0];
  const float* y  = (const float*)d_in[1];
  const float* wq = (const float*)d_in[2];
  const float* bq = (const float*)d_in[3];
  const float* wk = (const float*)d_in[4];
  const float* bk = (const float*)d_in[5];
  const float* wv = (const float*)d_in[6];
  const float* bv = (const float*)d_in[7];
  const float* wo = (const float*)d_in[8];
  const float* bo = (const float*)d_in[9];

  char* ws = (char*)d_ws;
  u16* QB   = (u16*)(ws + 0);            // 65536x1024 bf16 = 128 MB (Q, then attn out in-place)
  u16* WQ1T = (u16*)(ws + 134217728);    // [1024][1024] bf16, 2 MB
  u16* WO1T = (u16*)(ws + 136314880);    // 2 MB
  u16* WK2T = (u16*)(ws + 138412032);    // [1024][1536] bf16, 3 MB
  u16* WV2T = (u16*)(ws + 141557760);    // 3 MB
  u16* YB   = (u16*)(ws + 144703488);    // [1232][1536] bf16, 3.7 MB
  u16* KT   = (u16*)(ws + 148488192);    // [16][16][96][64] bf16, 3 MB
  u16* VT   = (u16*)(ws + 151633920);    // [16][16][64][96] bf16, 3 MB

  u16*   XB  = (u16*)d_out;   // x as bf16, first 128 MB of d_out (consumed before final write)
  float* OUT = (float*)d_out;

  // prep
  k_zero<<<768, 256, 0, stream>>>((u16x8*)KT, 786432);          // zero KT+VT (adjacent)
  k_cvt_x<<<4096, 256, 0, stream>>>(x, XB, 16777216);
  k_wt<<<2048, 256, 0, stream>>>(wq, WQ1T, 1024, 1024);
  k_wt<<<2048, 256, 0, stream>>>(wo, WO1T, 1024, 1024);
  k_split_w<<<1536, 256, 0, stream>>>(wk, WK2T, 768, 1024);
  k_split_w<<<1536, 256, 0, stream>>>(wv, WV2T, 768, 1024);
  k_prep_y<<<2048, 256, 0, stream>>>(y, YB);

  // K/V projections: M=1232 (=16*77), K=1536 (768 hi + 768 lo)
  gemm_bf16<2><<<80, 256, 0, stream>>>(YB, WK2T, bk, KT, 1232, 1536);
  gemm_bf16<3><<<80, 256, 0, stream>>>(YB, WV2T, bv, VT, 1232, 1536);

  // Q projection: 256^2 deep-pipelined GEMM, grid 256x4
  gemm256<0><<<1024, 512, 0, stream>>>(XB, WQ1T, bq, QB);

  // fused attention, in-place QB -> attn_out
  k_attn<<<8192, 256, 0, stream>>>(KT, VT, QB);

  // output projection -> f32 d_out
  gemm256<1><<<1024, 512, 0, stream>>>(QB, WO1T, bo, OUT);
}

// Round 5
// 639.458 us; speedup vs baseline: 1.1755x; 1.1755x over previous
//
#include <hip/hip_runtime.h>

typedef unsigned short u16;
typedef __attribute__((ext_vector_type(4))) float f32x4;
typedef __attribute__((ext_vector_type(8))) short bf16x8;
typedef __attribute__((ext_vector_type(8))) unsigned short u16x8;
typedef __attribute__((ext_vector_type(4))) unsigned short u16x4;

__device__ __forceinline__ u16 f2bf(float f) {
  union { float f; unsigned u; } v; v.f = f;
  unsigned r = v.u + 0x7FFFu + ((v.u >> 16) & 1u);
  return (u16)(r >> 16);
}
__device__ __forceinline__ float bf2f(u16 h) {
  union { unsigned u; float f; } v; v.u = ((unsigned)h) << 16; return v.f;
}

__device__ __forceinline__ void gload_lds16(const void* g, void* l) {
  __builtin_amdgcn_global_load_lds((const __attribute__((address_space(1))) void*)g,
                                   (__attribute__((address_space(3))) void*)l, 16, 0, 0);
}

// ---------------- prep kernels ----------------

__global__ void k_zero(u16x8* __restrict__ p, int n8) {
  int i = blockIdx.x * blockDim.x + threadIdx.x;
  int stride = gridDim.x * blockDim.x;
  u16x8 z = (u16x8)0;
  for (; i < n8; i += stride) p[i] = z;
}

__global__ void k_cvt_x(const float* __restrict__ in, u16* __restrict__ out, int n4) {
  int i = blockIdx.x * blockDim.x + threadIdx.x;
  int stride = gridDim.x * blockDim.x;
  const f32x4* in4 = (const f32x4*)in;
  u16x4* out4 = (u16x4*)out;
  for (; i < n4; i += stride) {
    f32x4 v = in4[i];
    u16x4 o;
    o[0] = f2bf(v[0]); o[1] = f2bf(v[1]); o[2] = f2bf(v[2]); o[3] = f2bf(v[3]);
    out4[i] = o;
  }
}

// w [K][N] f32 -> outT [N][K] bf16 (plain transpose)
__global__ void k_wt(const float* __restrict__ w, u16* __restrict__ outT, int K, int N) {
  int i = blockIdx.x * blockDim.x + threadIdx.x;
  int total = K * N;
  int stride = gridDim.x * blockDim.x;
  for (; i < total; i += stride) {
    int k = i / N, n = i - k * N;
    outT[(size_t)n * K + k] = f2bf(w[i]);
  }
}

// w [K][N] f32 -> outT [N][2K] bf16: rows n, cols 0..K-1 = hi, K..2K-1 = lo
__global__ void k_split_w(const float* __restrict__ w, u16* __restrict__ outT, int K, int N) {
  int i = blockIdx.x * blockDim.x + threadIdx.x;
  int total = K * N;
  int stride = gridDim.x * blockDim.x;
  for (; i < total; i += stride) {
    int k = i / N, n = i - k * N;
    float f = w[i];
    u16 hi = f2bf(f);
    u16 lo = f2bf(f - bf2f(hi));
    size_t o = (size_t)n * (2 * K) + k;
    outT[o] = hi;
    outT[o + K] = lo;
  }
}

// y [1232][768] f32 -> yb [1232][1536] bf16 (columns duplicated)
__global__ void k_prep_y(const float* __restrict__ y, u16* __restrict__ yb) {
  int i = blockIdx.x * blockDim.x + threadIdx.x;
  int total = 1232 * 1536;
  int stride = gridDim.x * blockDim.x;
  for (; i < total; i += stride) {
    int m = i / 1536, k = i - m * 1536;
    int ks = (k < 768) ? k : k - 768;
    yb[i] = f2bf(y[m * 768 + ks]);
  }
}

// ---------------- small GEMM (K/V projections), m97-style 128^2 ----------------
template <int EPI>
__global__ __launch_bounds__(256, 2) void gemm_bf16(
    const u16* __restrict__ A, const u16* __restrict__ B,
    const float* __restrict__ bias, void* __restrict__ outp,
    int M, int Kdim)
{
  __shared__ u16 sA[128 * 32];
  __shared__ u16 sB[128 * 32];
  const int t = threadIdx.x;
  const int ntiles = 8; // N = 1024
  const int bm = blockIdx.x / ntiles, bn = blockIdx.x % ntiles;
  const int m0 = bm * 128, n0 = bn * 128;
  const int l = t & 63, wv_ = t >> 6;
  const int lr = l & 15, lg = l >> 4;
  const int wm = (wv_ >> 1) * 64, wn = (wv_ & 1) * 64;

  const int srow = t >> 2;
  const int ssw = ((t >> 2) & 3) ^ ((t >> 4) & 3);
  const int scol = ((t & 3) ^ ssw) * 8;
  char* ldsA = (char*)sA;
  char* ldsB = (char*)sB;
  const int ldsoff = wv_ * 1024;

  const int swl = (lr & 3) ^ ((lr >> 2) & 3);
  const int rds = (lg ^ swl) * 8;

  f32x4 acc[4][4] = {};

  const int kiter = Kdim / 32;
  for (int kt = 0; kt < kiter; ++kt) {
    const int k0 = kt * 32;
    __syncthreads();
    {
      int r1 = m0 + srow;       if (r1 > M - 1) r1 = M - 1;
      int r2 = m0 + 64 + srow;  if (r2 > M - 1) r2 = M - 1;
      gload_lds16(A + (size_t)r1 * Kdim + k0 + scol, ldsA + 0    + ldsoff);
      gload_lds16(A + (size_t)r2 * Kdim + k0 + scol, ldsA + 4096 + ldsoff);
      gload_lds16(B + (size_t)(n0 + srow) * Kdim + k0 + scol,      ldsB + 0    + ldsoff);
      gload_lds16(B + (size_t)(n0 + 64 + srow) * Kdim + k0 + scol, ldsB + 4096 + ldsoff);
    }
    __syncthreads();
    bf16x8 af[4], bfr[4];
#pragma unroll
    for (int mt = 0; mt < 4; ++mt)
      af[mt] = *(const bf16x8*)&sA[(wm + mt * 16 + lr) * 32 + rds];
#pragma unroll
    for (int nt = 0; nt < 4; ++nt)
      bfr[nt] = *(const bf16x8*)&sB[(wn + nt * 16 + lr) * 32 + rds];
#pragma unroll
    for (int mt = 0; mt < 4; ++mt)
#pragma unroll
      for (int nt = 0; nt < 4; ++nt)
        acc[mt][nt] = __builtin_amdgcn_mfma_f32_16x16x32_bf16(af[mt], bfr[nt], acc[mt][nt], 0, 0, 0);
  }

#pragma unroll
  for (int mt = 0; mt < 4; ++mt) {
#pragma unroll
    for (int nt = 0; nt < 4; ++nt) {
      const int gc = n0 + wn + nt * 16 + lr;
      const float bb = bias[gc];
#pragma unroll
      for (int r = 0; r < 4; ++r) {
        const int gr = m0 + wm + mt * 16 + lg * 4 + r;
        const float v = acc[mt][nt][r] + bb;
        if constexpr (EPI == 2) {
          if (gr < M) {
            int bb2 = gr / 77, s = gr - bb2 * 77;
            int hh = gc >> 6, d = gc & 63;
            ((u16*)outp)[(((size_t)bb2 * 16 + hh) * 96 + s) * 64 + d] = f2bf(v);
          }
        } else {
          if (gr < M) {
            int bb2 = gr / 77, s = gr - bb2 * 77;
            int hh = gc >> 6, d = gc & 63;
            ((u16*)outp)[(((size_t)bb2 * 16 + hh) * 64 + d) * 96 + s] = f2bf(v);
          }
        }
      }
    }
  }
}

// ---------------- big GEMM: 256x128 tile, TRIPLE-buffered counted-vmcnt pipeline ----------------
// M = 65536, N = 1024, K = 1024. A [M][1024] bf16, B^T [1024 n][1024 k] bf16.
// 512 thr = 8 waves (4M x 2N): each wave owns a 64-row A half and 64-col B half.
// LDS 144KB = 3 buffers x (A 32KB + B 16KB). Stage tile c+2 during iter c (6 gload_lds,
// split 3+3 across the 2 phases). Invariant: after [vmcnt(6); barrier], all but the
// newest 6 loads (= tile c+2) are in LDS => tile c+1 fully landed before iter c+1 reads.
// Per K-tile: 2 phases { 8x ds_read_b128 (XOR-swz, 0-conflict) ; 3 stages ; SB0 ; BAR ;
// setprio 16 MFMA setprio ; BAR }. Tail peeled: c=14 waits vmcnt(0), c=15 clean.
template <int EPI>
__global__ __launch_bounds__(512, 2) void gemm256(
    const u16* __restrict__ A, const u16* __restrict__ Bp,
    const float* __restrict__ bias, void* __restrict__ outp)
{
  __shared__ char lds[147456];
  const int t = threadIdx.x;
  const int cpx = (int)gridDim.x >> 3;
  const int swz = ((int)blockIdx.x & 7) * cpx + ((int)blockIdx.x >> 3);
  const int bm = swz >> 3, bn = swz & 7;
  const int m0 = bm * 256, n0 = bn * 128;
  const int w = t >> 6, l = t & 63, lr = l & 15, lg = l >> 4;
  const int wm = w >> 1, wn = w & 1;   // 4 M-waves x 2 N-waves
  const int wbase = w * 1024;

  // staging: issue j covers rows j*64 + (t>>3); thread t -> LDS byte t*16 within block.
  const int srow = t >> 3;
  const int scol = ((t & 7) ^ (srow & 7)) << 3;   // inverse-swizzled global k-offset (elems)

  // read-side: frag rows have row&7 == lr&7; slot wanted (kk*4+lg) -> LDS slot ^(row&7)
  const int sw16_0 = ((lg) ^ (lr & 7)) << 4;
  const int sw16_1 = ((4 + lg) ^ (lr & 7)) << 4;
  const int arow = wm * 64 + lr;
  const int brow = wn * 64 + lr;

  f32x4 acc[4][4] = {};

#define RD_A(dst, rbb, ksw) { _Pragma("unroll") for (int q = 0; q < 4; ++q) \
    dst[q] = *(const bf16x8*)(lds + (rbb) + ((arow + q * 16) << 7) + (ksw)); }
#define RD_B(dst, rbb, ksw) { _Pragma("unroll") for (int nt = 0; nt < 4; ++nt) \
    dst[nt] = *(const bf16x8*)(lds + (rbb) + 32768 + ((brow + nt * 16) << 7) + (ksw)); }
#define STA1(kt, sbb, j) gload_lds16(A + (size_t)(m0 + (j) * 64 + srow) * 1024 + (kt) * 64 + scol, \
                                     lds + (sbb) + (j) * 8192 + wbase)
#define STB1(kt, sbb, j) gload_lds16(Bp + (size_t)(n0 + (j) * 64 + srow) * 1024 + (kt) * 64 + scol, \
                                     lds + (sbb) + 32768 + (j) * 8192 + wbase)
#define MM(a_, b_) { __builtin_amdgcn_s_setprio(1); \
  _Pragma("unroll") for (int q = 0; q < 4; ++q) \
    _Pragma("unroll") for (int nt = 0; nt < 4; ++nt) \
      acc[q][nt] = __builtin_amdgcn_mfma_f32_16x16x32_bf16(a_[q], b_[nt], acc[q][nt], 0, 0, 0); \
  __builtin_amdgcn_s_setprio(0); }
#define BAR __builtin_amdgcn_s_barrier()
#define SB0 __builtin_amdgcn_sched_barrier(0)

  // prologue: stage tile0 -> buf0, tile1 -> buf1; wait for tile0 only.
  STA1(0, 0, 0); STA1(0, 0, 1); STA1(0, 0, 2); STA1(0, 0, 3);
  STB1(0, 0, 0); STB1(0, 0, 1);
  STA1(1, 49152, 0); STA1(1, 49152, 1); STA1(1, 49152, 2); STA1(1, 49152, 3);
  STB1(1, 49152, 0); STB1(1, 49152, 1);
  asm volatile("s_waitcnt vmcnt(6)" ::: "memory");
  SB0; BAR;

  int rb = 0, sb = 2 * 49152;
#pragma unroll 1
  for (int c = 0; c < 14; ++c) {
    const int cs2 = c + 2;
    bf16x8 a0[4], b0[4], a1[4], b1[4];
    // phase 0 (kk=0): reads before barrier, consumed after; stage 3 of tile c+2
    RD_A(a0, rb, sw16_0); RD_B(b0, rb, sw16_0);
    STA1(cs2, sb, 0); STA1(cs2, sb, 1); STB1(cs2, sb, 0);
    SB0; BAR;
    MM(a0, b0); BAR;
    // phase 1 (kk=1): reads + remaining 3 stages; counted wait retires tile c+1
    RD_A(a1, rb, sw16_1); RD_B(b1, rb, sw16_1);
    STA1(cs2, sb, 2); STA1(cs2, sb, 3); STB1(cs2, sb, 1);
    asm volatile("s_waitcnt vmcnt(6)" ::: "memory");
    SB0; BAR;
    MM(a1, b1); BAR;
    rb += 49152; if (rb == 147456) rb = 0;
    sb += 49152; if (sb == 147456) sb = 0;
  }
  { // c = 14 (rb = buf2): no stage; drain tile15's loads at end
    bf16x8 a0[4], b0[4], a1[4], b1[4];
    RD_A(a0, rb, sw16_0); RD_B(b0, rb, sw16_0);
    SB0; BAR; MM(a0, b0); BAR;
    RD_A(a1, rb, sw16_1); RD_B(b1, rb, sw16_1);
    asm volatile("s_waitcnt vmcnt(0)" ::: "memory");
    SB0; BAR; MM(a1, b1); BAR;
    rb += 49152; if (rb == 147456) rb = 0;
  }
  { // c = 15 (rb = buf0): clean
    bf16x8 a0[4], b0[4], a1[4], b1[4];
    RD_A(a0, rb, sw16_0); RD_B(b0, rb, sw16_0);
    SB0; BAR; MM(a0, b0); BAR;
    RD_A(a1, rb, sw16_1); RD_B(b1, rb, sw16_1);
    SB0; BAR; MM(a1, b1);
  }

#undef RD_A
#undef RD_B
#undef STA1
#undef STB1
#undef MM
#undef BAR
#undef SB0

  // epilogue: C row = m0 + wm*64 + q*16 + lg*4 + r ; col = n0 + wn*64 + nt*16 + lr
#pragma unroll
  for (int q = 0; q < 4; ++q) {
#pragma unroll
    for (int nt = 0; nt < 4; ++nt) {
      const int gc = n0 + wn * 64 + nt * 16 + lr;
      const float bb = bias[gc];
#pragma unroll
      for (int r = 0; r < 4; ++r) {
        const int gr = m0 + wm * 64 + q * 16 + lg * 4 + r;
        const float v = acc[q][nt][r] + bb;
        if constexpr (EPI == 0) {
          ((u16*)outp)[(size_t)gr * 1024 + gc] = f2bf(v);
        } else {
          ((float*)outp)[(size_t)gr * 1024 + gc] = v;
        }
      }
    }
  }
}

// ---------------- fused attention ----------------
__global__ __launch_bounds__(256) void k_attn(const u16* __restrict__ KT,
                                              const u16* __restrict__ VT,
                                              u16* __restrict__ QB)
{
  __shared__ u16 sK[96 * 72];
  __shared__ u16 sV[64 * 104];
  __shared__ u16 sP[4][32 * 104];

  const int bid = blockIdx.x;
  const int h = bid & 15, b = (bid >> 4) & 15, blk = bid >> 8;
  const int t = threadIdx.x;

  const u16* gK = KT + (size_t)(b * 16 + h) * (96 * 64);
  const u16* gV = VT + (size_t)(b * 16 + h) * (64 * 96);
#pragma unroll
  for (int c = 0; c < 3; ++c) {
    int e = t * 8 + c * 2048;
    { int row = e >> 6, col = e & 63;
      *(u16x8*)&sK[row * 72 + col] = *(const u16x8*)&gK[e]; }
    { int row = e / 96, col = e - (e / 96) * 96;
      *(u16x8*)&sV[row * 104 + col] = *(const u16x8*)&gV[e]; }
  }
  __syncthreads();

  const int l = t & 63, w = t >> 6, lr = l & 15, lg = l >> 4;
  const size_t rowbase = (size_t)b * 4096 + blk * 128 + w * 32;

  bf16x8 aq[2][2];
#pragma unroll
  for (int mt = 0; mt < 2; ++mt)
#pragma unroll
    for (int ks = 0; ks < 2; ++ks)
      aq[mt][ks] = *(const bf16x8*)&QB[(rowbase + mt * 16 + lr) * 1024 + h * 64 + ks * 32 + lg * 8];

  f32x4 s_[2][5] = {};
#pragma unroll
  for (int nt = 0; nt < 5; ++nt) {
#pragma unroll
    for (int ks = 0; ks < 2; ++ks) {
      bf16x8 bk = *(const bf16x8*)&sK[(nt * 16 + lr) * 72 + ks * 32 + lg * 8];
#pragma unroll
      for (int mt = 0; mt < 2; ++mt)
        s_[mt][nt] = __builtin_amdgcn_mfma_f32_16x16x32_bf16(aq[mt][ks], bk, s_[mt][nt], 0, 0, 0);
    }
  }
#pragma unroll
  for (int mt = 0; mt < 2; ++mt)
#pragma unroll
    for (int nt = 0; nt < 5; ++nt)
#pragma unroll
      for (int r = 0; r < 4; ++r)
        s_[mt][nt][r] *= 0.125f;
  if (lr >= 13) {
#pragma unroll
    for (int mt = 0; mt < 2; ++mt)
#pragma unroll
      for (int r = 0; r < 4; ++r)
        s_[mt][4][r] = -1e30f;
  }

  float ri[2][4];
#pragma unroll
  for (int mt = 0; mt < 2; ++mt) {
#pragma unroll
    for (int r = 0; r < 4; ++r) {
      float m1 = s_[mt][0][r];
#pragma unroll
      for (int nt = 1; nt < 5; ++nt) m1 = fmaxf(m1, s_[mt][nt][r]);
      m1 = fmaxf(m1, __shfl_xor(m1, 1, 64));
      m1 = fmaxf(m1, __shfl_xor(m1, 2, 64));
      m1 = fmaxf(m1, __shfl_xor(m1, 4, 64));
      m1 = fmaxf(m1, __shfl_xor(m1, 8, 64));
      float s1 = 0.f;
#pragma unroll
      for (int nt = 0; nt < 5; ++nt) {
        float e = __expf(s_[mt][nt][r] - m1);
        s_[mt][nt][r] = e;
        s1 += e;
      }
      s1 += __shfl_xor(s1, 1, 64);
      s1 += __shfl_xor(s1, 2, 64);
      s1 += __shfl_xor(s1, 4, 64);
      s1 += __shfl_xor(s1, 8, 64);
      ri[mt][r] = 1.0f / s1;
    }
  }

#pragma unroll
  for (int mt = 0; mt < 2; ++mt)
#pragma unroll
    for (int nt = 0; nt < 5; ++nt)
#pragma unroll
      for (int r = 0; r < 4; ++r)
        sP[w][(mt * 16 + lg * 4 + r) * 104 + nt * 16 + lr] = f2bf(s_[mt][nt][r] * ri[mt][r]);
#pragma unroll
  for (int mt = 0; mt < 2; ++mt)
#pragma unroll
    for (int r = 0; r < 4; ++r)
      sP[w][(mt * 16 + lg * 4 + r) * 104 + 80 + lr] = 0;

  f32x4 o_[2][4] = {};
#pragma unroll
  for (int ks = 0; ks < 3; ++ks) {
    bf16x8 ap[2];
#pragma unroll
    for (int mt = 0; mt < 2; ++mt)
      ap[mt] = *(const bf16x8*)&sP[w][(mt * 16 + lr) * 104 + ks * 32 + lg * 8];
#pragma unroll
    for (int nt = 0; nt < 4; ++nt) {
      bf16x8 bv = *(const bf16x8*)&sV[(nt * 16 + lr) * 104 + ks * 32 + lg * 8];
#pragma unroll
      for (int mt = 0; mt < 2; ++mt)
        o_[mt][nt] = __builtin_amdgcn_mfma_f32_16x16x32_bf16(ap[mt], bv, o_[mt][nt], 0, 0, 0);
    }
  }

#pragma unroll
  for (int mt = 0; mt < 2; ++mt)
#pragma unroll
    for (int nt = 0; nt < 4; ++nt)
#pragma unroll
      for (int r = 0; r < 4; ++r)
        QB[(rowbase + mt * 16 + lg * 4 + r) * 1024 + h * 64 + nt * 16 + lr] = f2bf(o_[mt][nt][r]);
}

// ---------------- launch ----------------

extern "C" void kernel_launch(void* const* d_in, const int* in_sizes, int n_in,
                              void* d_out, int out_size, void* d_ws, size_t ws_size,
                              hipStream_t stream) {
  const float* x  = (const float*)d_in[0];
  const float* y  = (const float*)d_in[1];
  const float* wq = (const float*)d_in[2];
  const float* bq = (const float*)d_in[3];
  const float* wk = (const float*)d_in[4];
  const float* bk = (const float*)d_in[5];
  const float* wv = (const float*)d_in[6];
  const float* bv = (const float*)d_in[7];
  const float* wo = (const float*)d_in[8];
  const float* bo = (const float*)d_in[9];

  char* ws = (char*)d_ws;
  u16* QB   = (u16*)(ws + 0);            // 65536x1024 bf16 = 128 MB (Q, then attn out in-place)
  u16* WQ1T = (u16*)(ws + 134217728);    // [1024][1024] bf16, 2 MB
  u16* WO1T = (u16*)(ws + 136314880);    // 2 MB
  u16* WK2T = (u16*)(ws + 138412032);    // [1024][1536] bf16, 3 MB
  u16* WV2T = (u16*)(ws + 141557760);    // 3 MB
  u16* YB   = (u16*)(ws + 144703488);    // [1232][1536] bf16, 3.7 MB
  u16* KT   = (u16*)(ws + 148488192);    // [16][16][96][64] bf16, 3 MB
  u16* VT   = (u16*)(ws + 151633920);    // [16][16][64][96] bf16, 3 MB

  u16*   XB  = (u16*)d_out;   // x as bf16, first 128 MB of d_out (consumed before final write)
  float* OUT = (float*)d_out;

  // prep
  k_zero<<<768, 256, 0, stream>>>((u16x8*)KT, 786432);          // zero KT+VT (adjacent)
  k_cvt_x<<<4096, 256, 0, stream>>>(x, XB, 16777216);
  k_wt<<<2048, 256, 0, stream>>>(wq, WQ1T, 1024, 1024);
  k_wt<<<2048, 256, 0, stream>>>(wo, WO1T, 1024, 1024);
  k_split_w<<<1536, 256, 0, stream>>>(wk, WK2T, 768, 1024);
  k_split_w<<<1536, 256, 0, stream>>>(wv, WV2T, 768, 1024);
  k_prep_y<<<2048, 256, 0, stream>>>(y, YB);

  // K/V projections: M=1232 (=16*77), K=1536 (768 hi + 768 lo)
  gemm_bf16<2><<<80, 256, 0, stream>>>(YB, WK2T, bk, KT, 1232, 1536);
  gemm_bf16<3><<<80, 256, 0, stream>>>(YB, WV2T, bv, VT, 1232, 1536);

  // Q projection: 256x128 triple-buffered GEMM, grid 256 bm x 8 bn
  gemm256<0><<<2048, 512, 0, stream>>>(XB, WQ1T, bq, QB);

  // fused attention, in-place QB -> attn_out
  k_attn<<<8192, 256, 0, stream>>>(KT, VT, QB);

  // output projection -> f32 d_out
  gemm256<1><<<2048, 512, 0, stream>>>(QB, WO1T, bo, OUT);
}

// Round 6
// 564.091 us; speedup vs baseline: 1.3325x; 1.1336x over previous
//
#include <hip/hip_runtime.h>

typedef unsigned short u16;
typedef __attribute__((ext_vector_type(4))) float f32x4;
typedef __attribute__((ext_vector_type(8))) short bf16x8;
typedef __attribute__((ext_vector_type(8))) unsigned short u16x8;
typedef __attribute__((ext_vector_type(4))) unsigned short u16x4;

__device__ __forceinline__ u16 f2bf(float f) {
  union { float f; unsigned u; } v; v.f = f;
  unsigned r = v.u + 0x7FFFu + ((v.u >> 16) & 1u);
  return (u16)(r >> 16);
}
__device__ __forceinline__ float bf2f(u16 h) {
  union { unsigned u; float f; } v; v.u = ((unsigned)h) << 16; return v.f;
}

__device__ __forceinline__ void gload_lds16(const void* g, void* l) {
  __builtin_amdgcn_global_load_lds((const __attribute__((address_space(1))) void*)g,
                                   (__attribute__((address_space(3))) void*)l, 16, 0, 0);
}

// ---------------- prep kernels ----------------

__global__ void k_zero(u16x8* __restrict__ p, int n8) {
  int i = blockIdx.x * blockDim.x + threadIdx.x;
  int stride = gridDim.x * blockDim.x;
  u16x8 z = (u16x8)0;
  for (; i < n8; i += stride) p[i] = z;
}

__global__ void k_cvt_x(const float* __restrict__ in, u16* __restrict__ out, int n4) {
  int i = blockIdx.x * blockDim.x + threadIdx.x;
  int stride = gridDim.x * blockDim.x;
  const f32x4* in4 = (const f32x4*)in;
  u16x4* out4 = (u16x4*)out;
  for (; i < n4; i += stride) {
    f32x4 v = in4[i];
    u16x4 o;
    o[0] = f2bf(v[0]); o[1] = f2bf(v[1]); o[2] = f2bf(v[2]); o[3] = f2bf(v[3]);
    out4[i] = o;
  }
}

// all 4 weight transposes in one launch: w [K][1024] f32 -> [1024][K] bf16
__global__ void k_prep_w(const float* __restrict__ wq, const float* __restrict__ wo,
                         const float* __restrict__ wk, const float* __restrict__ wv,
                         u16* __restrict__ WQ1T, u16* __restrict__ WO1T,
                         u16* __restrict__ WK1T, u16* __restrict__ WV1T) {
  int bid = blockIdx.x;
  const float* w; u16* o; int K, k;
  if (bid < 1024)      { w = wq; o = WQ1T; K = 1024; k = bid; }
  else if (bid < 2048) { w = wo; o = WO1T; K = 1024; k = bid - 1024; }
  else if (bid < 2816) { w = wk; o = WK1T; K = 768;  k = bid - 2048; }
  else                 { w = wv; o = WV1T; K = 768;  k = bid - 2816; }
  for (int n = threadIdx.x; n < 1024; n += 256)
    o[(size_t)n * K + k] = f2bf(w[(size_t)k * 1024 + n]);
}

// y [1232][768] f32 -> yb bf16 (straight cvt)
__global__ void k_prep_y(const float* __restrict__ y, u16* __restrict__ yb, int n4) {
  int i = blockIdx.x * blockDim.x + threadIdx.x;
  int stride = gridDim.x * blockDim.x;
  const f32x4* in4 = (const f32x4*)y;
  u16x4* out4 = (u16x4*)yb;
  for (; i < n4; i += stride) {
    f32x4 v = in4[i];
    u16x4 o;
    o[0] = f2bf(v[0]); o[1] = f2bf(v[1]); o[2] = f2bf(v[2]); o[3] = f2bf(v[3]);
    out4[i] = o;
  }
}

// ---------------- K+V projections, merged, m97-style 128^2 ----------------
// M=1232, Kdim=768, N=1024. blocks 0..79 -> K proj, 80..159 -> V proj.
__global__ __launch_bounds__(256, 2) void k_gemm_kv(
    const u16* __restrict__ A,
    const u16* __restrict__ BK1, const float* __restrict__ bkb, u16* __restrict__ KTo,
    const u16* __restrict__ BV1, const float* __restrict__ bvb, u16* __restrict__ VTo)
{
  const int M = 1232, Kdim = 768;
  __shared__ u16 sA[128 * 32];
  __shared__ u16 sB[128 * 32];
  const int t = threadIdx.x;
  const int half = blockIdx.x >= 80;
  const int bb = blockIdx.x - half * 80;
  const u16* B = half ? BV1 : BK1;
  const float* bias = half ? bvb : bkb;
  u16* outp = half ? VTo : KTo;
  const int bm = bb / 8, bn = bb % 8;
  const int m0 = bm * 128, n0 = bn * 128;
  const int l = t & 63, wv_ = t >> 6;
  const int lr = l & 15, lg = l >> 4;
  const int wm = (wv_ >> 1) * 64, wn = (wv_ & 1) * 64;

  const int srow = t >> 2;
  const int ssw = ((t >> 2) & 3) ^ ((t >> 4) & 3);
  const int scol = ((t & 3) ^ ssw) * 8;
  char* ldsA = (char*)sA;
  char* ldsB = (char*)sB;
  const int ldsoff = wv_ * 1024;

  const int swl = (lr & 3) ^ ((lr >> 2) & 3);
  const int rds = (lg ^ swl) * 8;

  f32x4 acc[4][4] = {};

  for (int kt = 0; kt < Kdim / 32; ++kt) {
    const int k0 = kt * 32;
    __syncthreads();
    {
      int r1 = m0 + srow;       if (r1 > M - 1) r1 = M - 1;
      int r2 = m0 + 64 + srow;  if (r2 > M - 1) r2 = M - 1;
      gload_lds16(A + (size_t)r1 * Kdim + k0 + scol, ldsA + 0    + ldsoff);
      gload_lds16(A + (size_t)r2 * Kdim + k0 + scol, ldsA + 4096 + ldsoff);
      gload_lds16(B + (size_t)(n0 + srow) * Kdim + k0 + scol,      ldsB + 0    + ldsoff);
      gload_lds16(B + (size_t)(n0 + 64 + srow) * Kdim + k0 + scol, ldsB + 4096 + ldsoff);
    }
    __syncthreads();
    bf16x8 af[4], bfr[4];
#pragma unroll
    for (int mt = 0; mt < 4; ++mt)
      af[mt] = *(const bf16x8*)&sA[(wm + mt * 16 + lr) * 32 + rds];
#pragma unroll
    for (int nt = 0; nt < 4; ++nt)
      bfr[nt] = *(const bf16x8*)&sB[(wn + nt * 16 + lr) * 32 + rds];
#pragma unroll
    for (int mt = 0; mt < 4; ++mt)
#pragma unroll
      for (int nt = 0; nt < 4; ++nt)
        acc[mt][nt] = __builtin_amdgcn_mfma_f32_16x16x32_bf16(af[mt], bfr[nt], acc[mt][nt], 0, 0, 0);
  }

#pragma unroll
  for (int mt = 0; mt < 4; ++mt) {
#pragma unroll
    for (int nt = 0; nt < 4; ++nt) {
      const int gc = n0 + wn + nt * 16 + lr;
      const float bb2 = bias[gc];
#pragma unroll
      for (int r = 0; r < 4; ++r) {
        const int gr = m0 + wm + mt * 16 + lg * 4 + r;
        const float v = acc[mt][nt][r] + bb2;
        if (gr < M) {
          int bI = gr / 77, s = gr - bI * 77;
          int hh = gc >> 6, d = gc & 63;
          if (!half)  // K: [b][h][96 s][64 d]
            outp[(((size_t)bI * 16 + hh) * 96 + s) * 64 + d] = f2bf(v);
          else        // V: [b][h][64 d][96 s]
            outp[(((size_t)bI * 16 + hh) * 64 + d) * 96 + s] = f2bf(v);
        }
      }
    }
  }
}

// ---------------- big GEMM: 256x128 tile, BK=32, triple-buffer, 2 blocks/CU ----------------
// M=65536, N=1024, K=1024. A [M][1024] bf16, B^T [1024][1024] bf16.
// 512 thr = 8 waves (4M x 2N), wave output 64x64. LDS 72KB = 3 x (A 16KB + B 8KB)
// -> 2 blocks/CU, 4 waves/SIMD: independent blocks de-phase and overlap read/MFMA.
// Per K-tile: {8 ds_read_b128 (swz) ; stage tile c+2 (3 gload_lds) ; vmcnt(3) ; BAR ;
//   16 MFMA ; BAR}. vmcnt(3): 6 outstanding -> retires tile c+1 exactly. Never 0 in loop.
// Swizzle (64B rows, 4 slots): LDS[row][s] = global slot s^(row&3)^((row>>2)&3);
// balanced banks: conflict-free (2 lanes per 4-bank group per 16-lane quarter).
template <int EPI>
__global__ __launch_bounds__(512, 4) void gemm256(
    const u16* __restrict__ A, const u16* __restrict__ Bp,
    const float* __restrict__ bias, void* __restrict__ outp)
{
  __shared__ char lds[73728];
  const int t = threadIdx.x;
  const int cpx = (int)gridDim.x >> 3;
  const int swz = ((int)blockIdx.x & 7) * cpx + ((int)blockIdx.x >> 3);
  const int bm = swz >> 3, bn = swz & 7;
  const int m0 = bm * 256, n0 = bn * 128;
  const int w = t >> 6, l = t & 63, lr = l & 15, lg = l >> 4;
  const int wm = w >> 1, wn = w & 1;   // 4 M-waves x 2 N-waves

  // staging: thread t -> LDS byte t*16 (row t>>2, slot t&3); inverse-swizzled global slot
  const int srow = t >> 2;                                      // 0..127 per issue
  const int scol = ((t & 3) ^ ((t >> 2) & 3) ^ ((t >> 4) & 3)) * 8;  // elems
  // read-side: want global slot lg at row; LDS slot = lg ^ (lr&3) ^ ((lr>>2)&3)
  const int rsw = (lg ^ (lr & 3) ^ ((lr >> 2) & 3)) << 4;       // bytes
  const int arow = wm * 64 + lr;
  const int brow = wn * 64 + lr;

  f32x4 acc[4][4] = {};

#define RD_A(dst, rbb) { _Pragma("unroll") for (int q = 0; q < 4; ++q) \
    dst[q] = *(const bf16x8*)(lds + (rbb) + ((arow + q * 16) << 6) + rsw); }
#define RD_B(dst, rbb) { _Pragma("unroll") for (int nt = 0; nt < 4; ++nt) \
    dst[nt] = *(const bf16x8*)(lds + (rbb) + 16384 + ((brow + nt * 16) << 6) + rsw); }
#define STAGE(kt, sbb) { \
    gload_lds16(A + (size_t)(m0 + srow) * 1024 + (kt) * 32 + scol,       lds + (sbb) + t * 16); \
    gload_lds16(A + (size_t)(m0 + 128 + srow) * 1024 + (kt) * 32 + scol, lds + (sbb) + 8192 + t * 16); \
    gload_lds16(Bp + (size_t)(n0 + srow) * 1024 + (kt) * 32 + scol,      lds + (sbb) + 16384 + t * 16); }
#define MM(a_, b_) { __builtin_amdgcn_s_setprio(1); \
  _Pragma("unroll") for (int q = 0; q < 4; ++q) \
    _Pragma("unroll") for (int nt = 0; nt < 4; ++nt) \
      acc[q][nt] = __builtin_amdgcn_mfma_f32_16x16x32_bf16(a_[q], b_[nt], acc[q][nt], 0, 0, 0); \
  __builtin_amdgcn_s_setprio(0); }
#define BAR __builtin_amdgcn_s_barrier()
#define SB0 __builtin_amdgcn_sched_barrier(0)

  // prologue: stage tiles 0 -> buf0, 1 -> buf1; wait for tile 0 only (3 newest fly)
  STAGE(0, 0);
  STAGE(1, 24576);
  asm volatile("s_waitcnt vmcnt(3)" ::: "memory");
  SB0; BAR;

  int rb = 0, sb = 2 * 24576;
#pragma unroll 1
  for (int c = 0; c < 30; ++c) {
    bf16x8 a_[4], b_[4];
    RD_A(a_, rb); RD_B(b_, rb);
    STAGE(c + 2, sb);
    asm volatile("s_waitcnt vmcnt(3)" ::: "memory");  // retires tile c+1; c+2 stays in flight
    SB0; BAR;
    MM(a_, b_); BAR;
    rb += 24576; if (rb == 73728) rb = 0;
    sb += 24576; if (sb == 73728) sb = 0;
  }
  { // c = 30: no stage; drain tile 31's loads
    bf16x8 a_[4], b_[4];
    RD_A(a_, rb); RD_B(b_, rb);
    asm volatile("s_waitcnt vmcnt(0)" ::: "memory");
    SB0; BAR;
    MM(a_, b_); BAR;
    rb += 24576; if (rb == 73728) rb = 0;
  }
  { // c = 31
    bf16x8 a_[4], b_[4];
    RD_A(a_, rb); RD_B(b_, rb);
    SB0; BAR;
    MM(a_, b_);
  }

#undef RD_A
#undef RD_B
#undef STAGE
#undef MM
#undef BAR
#undef SB0

  // epilogue: C row = m0 + wm*64 + q*16 + lg*4 + r ; col = n0 + wn*64 + nt*16 + lr
#pragma unroll
  for (int q = 0; q < 4; ++q) {
#pragma unroll
    for (int nt = 0; nt < 4; ++nt) {
      const int gc = n0 + wn * 64 + nt * 16 + lr;
      const float bb = bias[gc];
#pragma unroll
      for (int r = 0; r < 4; ++r) {
        const int gr = m0 + wm * 64 + q * 16 + lg * 4 + r;
        const float v = acc[q][nt][r] + bb;
        if constexpr (EPI == 0) {
          ((u16*)outp)[(size_t)gr * 1024 + gc] = f2bf(v);
        } else {
          ((float*)outp)[(size_t)gr * 1024 + gc] = v;
        }
      }
    }
  }
}

// ---------------- fused attention ----------------
__global__ __launch_bounds__(256) void k_attn(const u16* __restrict__ KT,
                                              const u16* __restrict__ VT,
                                              u16* __restrict__ QB)
{
  __shared__ u16 sK[96 * 72];
  __shared__ u16 sV[64 * 104];
  __shared__ u16 sP[4][32 * 104];

  const int bid = blockIdx.x;
  const int h = bid & 15, b = (bid >> 4) & 15, blk = bid >> 8;
  const int t = threadIdx.x;

  const u16* gK = KT + (size_t)(b * 16 + h) * (96 * 64);
  const u16* gV = VT + (size_t)(b * 16 + h) * (64 * 96);
#pragma unroll
  for (int c = 0; c < 3; ++c) {
    int e = t * 8 + c * 2048;
    { int row = e >> 6, col = e & 63;
      *(u16x8*)&sK[row * 72 + col] = *(const u16x8*)&gK[e]; }
    { int row = e / 96, col = e - (e / 96) * 96;
      *(u16x8*)&sV[row * 104 + col] = *(const u16x8*)&gV[e]; }
  }
  __syncthreads();

  const int l = t & 63, w = t >> 6, lr = l & 15, lg = l >> 4;
  const size_t rowbase = (size_t)b * 4096 + blk * 128 + w * 32;

  bf16x8 aq[2][2];
#pragma unroll
  for (int mt = 0; mt < 2; ++mt)
#pragma unroll
    for (int ks = 0; ks < 2; ++ks)
      aq[mt][ks] = *(const bf16x8*)&QB[(rowbase + mt * 16 + lr) * 1024 + h * 64 + ks * 32 + lg * 8];

  f32x4 s_[2][5] = {};
#pragma unroll
  for (int nt = 0; nt < 5; ++nt) {
#pragma unroll
    for (int ks = 0; ks < 2; ++ks) {
      bf16x8 bk = *(const bf16x8*)&sK[(nt * 16 + lr) * 72 + ks * 32 + lg * 8];
#pragma unroll
      for (int mt = 0; mt < 2; ++mt)
        s_[mt][nt] = __builtin_amdgcn_mfma_f32_16x16x32_bf16(aq[mt][ks], bk, s_[mt][nt], 0, 0, 0);
    }
  }
#pragma unroll
  for (int mt = 0; mt < 2; ++mt)
#pragma unroll
    for (int nt = 0; nt < 5; ++nt)
#pragma unroll
      for (int r = 0; r < 4; ++r)
        s_[mt][nt][r] *= 0.125f;
  if (lr >= 13) {
#pragma unroll
    for (int mt = 0; mt < 2; ++mt)
#pragma unroll
      for (int r = 0; r < 4; ++r)
        s_[mt][4][r] = -1e30f;
  }

  float ri[2][4];
#pragma unroll
  for (int mt = 0; mt < 2; ++mt) {
#pragma unroll
    for (int r = 0; r < 4; ++r) {
      float m1 = s_[mt][0][r];
#pragma unroll
      for (int nt = 1; nt < 5; ++nt) m1 = fmaxf(m1, s_[mt][nt][r]);
      m1 = fmaxf(m1, __shfl_xor(m1, 1, 64));
      m1 = fmaxf(m1, __shfl_xor(m1, 2, 64));
      m1 = fmaxf(m1, __shfl_xor(m1, 4, 64));
      m1 = fmaxf(m1, __shfl_xor(m1, 8, 64));
      float s1 = 0.f;
#pragma unroll
      for (int nt = 0; nt < 5; ++nt) {
        float e = __expf(s_[mt][nt][r] - m1);
        s_[mt][nt][r] = e;
        s1 += e;
      }
      s1 += __shfl_xor(s1, 1, 64);
      s1 += __shfl_xor(s1, 2, 64);
      s1 += __shfl_xor(s1, 4, 64);
      s1 += __shfl_xor(s1, 8, 64);
      ri[mt][r] = 1.0f / s1;
    }
  }

#pragma unroll
  for (int mt = 0; mt < 2; ++mt)
#pragma unroll
    for (int nt = 0; nt < 5; ++nt)
#pragma unroll
      for (int r = 0; r < 4; ++r)
        sP[w][(mt * 16 + lg * 4 + r) * 104 + nt * 16 + lr] = f2bf(s_[mt][nt][r] * ri[mt][r]);
#pragma unroll
  for (int mt = 0; mt < 2; ++mt)
#pragma unroll
    for (int r = 0; r < 4; ++r)
      sP[w][(mt * 16 + lg * 4 + r) * 104 + 80 + lr] = 0;

  f32x4 o_[2][4] = {};
#pragma unroll
  for (int ks = 0; ks < 3; ++ks) {
    bf16x8 ap[2];
#pragma unroll
    for (int mt = 0; mt < 2; ++mt)
      ap[mt] = *(const bf16x8*)&sP[w][(mt * 16 + lr) * 104 + ks * 32 + lg * 8];
#pragma unroll
    for (int nt = 0; nt < 4; ++nt) {
      bf16x8 bv = *(const bf16x8*)&sV[(nt * 16 + lr) * 104 + ks * 32 + lg * 8];
#pragma unroll
      for (int mt = 0; mt < 2; ++mt)
        o_[mt][nt] = __builtin_amdgcn_mfma_f32_16x16x32_bf16(ap[mt], bv, o_[mt][nt], 0, 0, 0);
    }
  }

#pragma unroll
  for (int mt = 0; mt < 2; ++mt)
#pragma unroll
    for (int nt = 0; nt < 4; ++nt)
#pragma unroll
      for (int r = 0; r < 4; ++r)
        QB[(rowbase + mt * 16 + lg * 4 + r) * 1024 + h * 64 + nt * 16 + lr] = f2bf(o_[mt][nt][r]);
}

// ---------------- launch ----------------

extern "C" void kernel_launch(void* const* d_in, const int* in_sizes, int n_in,
                              void* d_out, int out_size, void* d_ws, size_t ws_size,
                              hipStream_t stream) {
  const float* x  = (const float*)d_in[0];
  const float* y  = (const float*)d_in[1];
  const float* wq = (const float*)d_in[2];
  const float* bq = (const float*)d_in[3];
  const float* wk = (const float*)d_in[4];
  const float* bk = (const float*)d_in[5];
  const float* wv = (const float*)d_in[6];
  const float* bv = (const float*)d_in[7];
  const float* wo = (const float*)d_in[8];
  const float* bo = (const float*)d_in[9];

  char* ws = (char*)d_ws;
  u16* QB   = (u16*)(ws + 0);            // 65536x1024 bf16 = 128 MB (Q, then attn out in-place)
  u16* WQ1T = (u16*)(ws + 134217728);    // [1024][1024] bf16, 2 MB
  u16* WO1T = (u16*)(ws + 136314880);    // 2 MB
  u16* WK1T = (u16*)(ws + 138412032);    // [1024][768] bf16, 1.5 MB
  u16* WV1T = (u16*)(ws + 139984896);    // 1.5 MB
  u16* YB   = (u16*)(ws + 141557760);    // [1232][768] bf16, 1.85 MB
  u16* KT   = (u16*)(ws + 143654912);    // [16][16][96][64] bf16, 3 MB
  u16* VT   = (u16*)(ws + 146800640);    // [16][16][64][96] bf16, 3 MB

  u16*   XB  = (u16*)d_out;   // x as bf16, first 128 MB of d_out (consumed before final write)
  float* OUT = (float*)d_out;

  // prep
  k_zero<<<768, 256, 0, stream>>>((u16x8*)KT, 393216);          // zero KT+VT (adjacent, 6 MB)
  k_cvt_x<<<4096, 256, 0, stream>>>(x, XB, 16777216);
  k_prep_w<<<3584, 256, 0, stream>>>(wq, wo, wk, wv, WQ1T, WO1T, WK1T, WV1T);
  k_prep_y<<<924, 256, 0, stream>>>(y, YB, 236544);

  // K+V projections (one launch): M=1232, K=768
  k_gemm_kv<<<160, 256, 0, stream>>>(YB, WK1T, bk, KT, WV1T, bv, VT);

  // Q projection: 256x128 BK=32 triple-buffered GEMM, grid 256 bm x 8 bn
  gemm256<0><<<2048, 512, 0, stream>>>(XB, WQ1T, bq, QB);

  // fused attention, in-place QB -> attn_out
  k_attn<<<8192, 256, 0, stream>>>(KT, VT, QB);

  // output projection -> f32 d_out
  gemm256<1><<<2048, 512, 0, stream>>>(QB, WO1T, bo, OUT);
}

// Round 8
// 562.765 us; speedup vs baseline: 1.3356x; 1.0024x over previous
//
#include <hip/hip_runtime.h>

typedef unsigned short u16;
typedef __attribute__((ext_vector_type(4))) float f32x4;
typedef __attribute__((ext_vector_type(8))) short bf16x8;
typedef __attribute__((ext_vector_type(8))) unsigned short u16x8;
typedef __attribute__((ext_vector_type(4))) unsigned short u16x4;

__device__ __forceinline__ u16 f2bf(float f) {
  union { float f; unsigned u; } v; v.f = f;
  unsigned r = v.u + 0x7FFFu + ((v.u >> 16) & 1u);
  return (u16)(r >> 16);
}
__device__ __forceinline__ float bf2f(u16 h) {
  union { unsigned u; float f; } v; v.u = ((unsigned)h) << 16; return v.f;
}

__device__ __forceinline__ void gload_lds16(const void* g, void* l) {
  __builtin_amdgcn_global_load_lds((const __attribute__((address_space(1))) void*)g,
                                   (__attribute__((address_space(3))) void*)l, 16, 0, 0);
}

// ---------------- prep kernels ----------------

__global__ void k_zero(u16x8* __restrict__ p, int n8) {
  int i = blockIdx.x * blockDim.x + threadIdx.x;
  int stride = gridDim.x * blockDim.x;
  u16x8 z = (u16x8)0;
  for (; i < n8; i += stride) p[i] = z;
}

__global__ void k_cvt_x(const float* __restrict__ in, u16* __restrict__ out, int n4) {
  int i = blockIdx.x * blockDim.x + threadIdx.x;
  int stride = gridDim.x * blockDim.x;
  const f32x4* in4 = (const f32x4*)in;
  u16x4* out4 = (u16x4*)out;
  for (; i < n4; i += stride) {
    f32x4 v = in4[i];
    u16x4 o;
    o[0] = f2bf(v[0]); o[1] = f2bf(v[1]); o[2] = f2bf(v[2]); o[3] = f2bf(v[3]);
    out4[i] = o;
  }
}

// all 4 weight transposes in one launch: w [K][1024] f32 -> [1024][K] bf16
__global__ void k_prep_w(const float* __restrict__ wq, const float* __restrict__ wo,
                         const float* __restrict__ wk, const float* __restrict__ wv,
                         u16* __restrict__ WQ1T, u16* __restrict__ WO1T,
                         u16* __restrict__ WK1T, u16* __restrict__ WV1T) {
  int bid = blockIdx.x;
  const float* w; u16* o; int K, k;
  if (bid < 1024)      { w = wq; o = WQ1T; K = 1024; k = bid; }
  else if (bid < 2048) { w = wo; o = WO1T; K = 1024; k = bid - 1024; }
  else if (bid < 2816) { w = wk; o = WK1T; K = 768;  k = bid - 2048; }
  else                 { w = wv; o = WV1T; K = 768;  k = bid - 2816; }
  for (int n = threadIdx.x; n < 1024; n += 256)
    o[(size_t)n * K + k] = f2bf(w[(size_t)k * 1024 + n]);
}

// y [1232][768] f32 -> yb bf16 (straight cvt)
__global__ void k_prep_y(const float* __restrict__ y, u16* __restrict__ yb, int n4) {
  int i = blockIdx.x * blockDim.x + threadIdx.x;
  int stride = gridDim.x * blockDim.x;
  const f32x4* in4 = (const f32x4*)y;
  u16x4* out4 = (u16x4*)yb;
  for (; i < n4; i += stride) {
    f32x4 v = in4[i];
    u16x4 o;
    o[0] = f2bf(v[0]); o[1] = f2bf(v[1]); o[2] = f2bf(v[2]); o[3] = f2bf(v[3]);
    out4[i] = o;
  }
}

// ---------------- K+V projections, merged, m97-style 128^2 ----------------
__global__ __launch_bounds__(256, 2) void k_gemm_kv(
    const u16* __restrict__ A,
    const u16* __restrict__ BK1, const float* __restrict__ bkb, u16* __restrict__ KTo,
    const u16* __restrict__ BV1, const float* __restrict__ bvb, u16* __restrict__ VTo)
{
  const int M = 1232, Kdim = 768;
  __shared__ u16 sA[128 * 32];
  __shared__ u16 sB[128 * 32];
  const int t = threadIdx.x;
  const int half = blockIdx.x >= 80;
  const int bb = blockIdx.x - half * 80;
  const u16* B = half ? BV1 : BK1;
  const float* bias = half ? bvb : bkb;
  u16* outp = half ? VTo : KTo;
  const int bm = bb / 8, bn = bb % 8;
  const int m0 = bm * 128, n0 = bn * 128;
  const int l = t & 63, wv_ = t >> 6;
  const int lr = l & 15, lg = l >> 4;
  const int wm = (wv_ >> 1) * 64, wn = (wv_ & 1) * 64;

  const int srow = t >> 2;
  const int ssw = ((t >> 2) & 3) ^ ((t >> 4) & 3);
  const int scol = ((t & 3) ^ ssw) * 8;
  char* ldsA = (char*)sA;
  char* ldsB = (char*)sB;
  const int ldsoff = wv_ * 1024;

  const int swl = (lr & 3) ^ ((lr >> 2) & 3);
  const int rds = (lg ^ swl) * 8;

  f32x4 acc[4][4] = {};

  for (int kt = 0; kt < Kdim / 32; ++kt) {
    const int k0 = kt * 32;
    __syncthreads();
    {
      int r1 = m0 + srow;       if (r1 > M - 1) r1 = M - 1;
      int r2 = m0 + 64 + srow;  if (r2 > M - 1) r2 = M - 1;
      gload_lds16(A + (size_t)r1 * Kdim + k0 + scol, ldsA + 0    + ldsoff);
      gload_lds16(A + (size_t)r2 * Kdim + k0 + scol, ldsA + 4096 + ldsoff);
      gload_lds16(B + (size_t)(n0 + srow) * Kdim + k0 + scol,      ldsB + 0    + ldsoff);
      gload_lds16(B + (size_t)(n0 + 64 + srow) * Kdim + k0 + scol, ldsB + 4096 + ldsoff);
    }
    __syncthreads();
    bf16x8 af[4], bfr[4];
#pragma unroll
    for (int mt = 0; mt < 4; ++mt)
      af[mt] = *(const bf16x8*)&sA[(wm + mt * 16 + lr) * 32 + rds];
#pragma unroll
    for (int nt = 0; nt < 4; ++nt)
      bfr[nt] = *(const bf16x8*)&sB[(wn + nt * 16 + lr) * 32 + rds];
#pragma unroll
    for (int mt = 0; mt < 4; ++mt)
#pragma unroll
      for (int nt = 0; nt < 4; ++nt)
        acc[mt][nt] = __builtin_amdgcn_mfma_f32_16x16x32_bf16(af[mt], bfr[nt], acc[mt][nt], 0, 0, 0);
  }

#pragma unroll
  for (int mt = 0; mt < 4; ++mt) {
#pragma unroll
    for (int nt = 0; nt < 4; ++nt) {
      const int gc = n0 + wn + nt * 16 + lr;
      const float bb2 = bias[gc];
#pragma unroll
      for (int r = 0; r < 4; ++r) {
        const int gr = m0 + wm + mt * 16 + lg * 4 + r;
        const float v = acc[mt][nt][r] + bb2;
        if (gr < M) {
          int bI = gr / 77, s = gr - bI * 77;
          int hh = gc >> 6, d = gc & 63;
          if (!half)
            outp[(((size_t)bI * 16 + hh) * 96 + s) * 64 + d] = f2bf(v);
          else
            outp[(((size_t)bI * 16 + hh) * 64 + d) * 96 + s] = f2bf(v);
        }
      }
    }
  }
}

// ---------------- big GEMM: 256x256 tile, BK=32, triple-buffer, wave 128x64 ----------------
// M=65536, N=1024, K=1024. A [M][1024] bf16, B^T [1024][1024] bf16.
// 512 thr = 8 waves (2M x 4N), wave output 128x64 -> per K-tile: 12 ds_read_b128 vs
// 32 MFMA/wave (256/CU ~1242 cyc > LDS 96KB ~768 cyc -> MFMA-pipe dominant).
// LDS 96KB = 3 bufs x (A 16KB + B 16KB). Stage tile c+2 during iter c (4 gload_lds).
// ORDER (the r7 lesson): reads(buf c) ; stage(c+2) ; vmcnt(4) ; barrier ; MFMA ; barrier.
// vmcnt(4) BEFORE the barrier retires tile c+1 in every wave => safe to read after BAR.
// Stage overwrites buf[(c+2)%3] = buffer read in iter c-1, whose reads completed before
// iter c-1's MFMA (lgkmcnt) and whose waves passed the end-of-iter barrier. Never 0 in loop.
template <int EPI>
__global__ __launch_bounds__(512, 2) void gemm256(
    const u16* __restrict__ A, const u16* __restrict__ Bp,
    const float* __restrict__ bias, void* __restrict__ outp)
{
  __shared__ char lds[98304];
  const int t = threadIdx.x;
  const int cpx = (int)gridDim.x >> 3;
  const int swz = ((int)blockIdx.x & 7) * cpx + ((int)blockIdx.x >> 3);
  const int bm = swz >> 2, bn = swz & 3;
  const int m0 = bm * 256, n0 = bn * 256;
  const int w = t >> 6, l = t & 63, lr = l & 15, lg = l >> 4;
  const int wm = w >> 2, wn = w & 3;   // 2 M-waves x 4 N-waves, wave tile 128x64

  // staging: thread t -> LDS byte t*16 (row t>>2 within 128-row issue, slot t&3);
  // global k-slot pre-swizzled so LDS[row][s] = global slot s ^ (r&3) ^ ((r>>2)&3)
  const int srow = t >> 2;
  const int scol = ((t & 3) ^ ((t >> 2) & 3) ^ ((t >> 4) & 3)) * 8;  // elems
  // read-side: want global slot lg at row; LDS slot = lg ^ (lr&3) ^ ((lr>>2)&3)
  const int rsw = (lg ^ (lr & 3) ^ ((lr >> 2) & 3)) << 4;            // bytes
  const int arow = wm * 128 + lr;
  const int brow = wn * 64 + lr;

  f32x4 acc[8][4] = {};

#define RD_A(dst, rbb) { _Pragma("unroll") for (int q = 0; q < 8; ++q) \
    dst[q] = *(const bf16x8*)(lds + (rbb) + ((arow + q * 16) << 6) + rsw); }
#define RD_B(dst, rbb) { _Pragma("unroll") for (int nt = 0; nt < 4; ++nt) \
    dst[nt] = *(const bf16x8*)(lds + (rbb) + 16384 + ((brow + nt * 16) << 6) + rsw); }
#define STAGE(kt, sbb) { \
    gload_lds16(A + (size_t)(m0 + srow) * 1024 + (kt) * 32 + scol,        lds + (sbb) + t * 16); \
    gload_lds16(A + (size_t)(m0 + 128 + srow) * 1024 + (kt) * 32 + scol,  lds + (sbb) + 8192 + t * 16); \
    gload_lds16(Bp + (size_t)(n0 + srow) * 1024 + (kt) * 32 + scol,       lds + (sbb) + 16384 + t * 16); \
    gload_lds16(Bp + (size_t)(n0 + 128 + srow) * 1024 + (kt) * 32 + scol, lds + (sbb) + 24576 + t * 16); }
#define MM(a_, b_) { __builtin_amdgcn_s_setprio(1); \
  _Pragma("unroll") for (int q = 0; q < 8; ++q) \
    _Pragma("unroll") for (int nt = 0; nt < 4; ++nt) \
      acc[q][nt] = __builtin_amdgcn_mfma_f32_16x16x32_bf16(a_[q], b_[nt], acc[q][nt], 0, 0, 0); \
  __builtin_amdgcn_s_setprio(0); }
#define BAR __builtin_amdgcn_s_barrier()
#define SB0 __builtin_amdgcn_sched_barrier(0)

  // prologue: stage tiles 0 -> buf0, 1 -> buf1; vmcnt(4) retires tile 0; BAR; loop reads.
  STAGE(0, 0);
  STAGE(1, 32768);
  asm volatile("s_waitcnt vmcnt(4)" ::: "memory");
  SB0; BAR;

  int rb = 0, sb = 2 * 32768;
#pragma unroll 1
  for (int c = 0; c < 30; ++c) {
    bf16x8 a_[8], b_[4];
    RD_A(a_, rb); RD_B(b_, rb);
    STAGE(c + 2, sb);
    asm volatile("s_waitcnt vmcnt(4)" ::: "memory");  // retires tile c+1; c+2 stays in flight
    SB0; BAR;
    MM(a_, b_); BAR;
    rb += 32768; if (rb == 98304) rb = 0;
    sb += 32768; if (sb == 98304) sb = 0;
  }
  { // c = 30 (buf0): no stage; drain tile 31's loads before BAR
    bf16x8 a_[8], b_[4];
    RD_A(a_, rb); RD_B(b_, rb);
    asm volatile("s_waitcnt vmcnt(0)" ::: "memory");
    SB0; BAR;
    MM(a_, b_); BAR;
    rb += 32768; if (rb == 98304) rb = 0;
  }
  { // c = 31 (buf1)
    bf16x8 a_[8], b_[4];
    RD_A(a_, rb); RD_B(b_, rb);
    SB0; BAR;
    MM(a_, b_);
  }

#undef RD_A
#undef RD_B
#undef STAGE
#undef MM
#undef BAR
#undef SB0

  // epilogue: C row = m0 + wm*128 + q*16 + lg*4 + r ; col = n0 + wn*64 + nt*16 + lr
#pragma unroll
  for (int q = 0; q < 8; ++q) {
#pragma unroll
    for (int nt = 0; nt < 4; ++nt) {
      const int gc = n0 + wn * 64 + nt * 16 + lr;
      const float bb = bias[gc];
#pragma unroll
      for (int r = 0; r < 4; ++r) {
        const int gr = m0 + wm * 128 + q * 16 + lg * 4 + r;
        const float v = acc[q][nt][r] + bb;
        if constexpr (EPI == 0) {
          ((u16*)outp)[(size_t)gr * 1024 + gc] = f2bf(v);
        } else {
          ((float*)outp)[(size_t)gr * 1024 + gc] = v;
        }
      }
    }
  }
}

// ---------------- fused attention ----------------
__global__ __launch_bounds__(256) void k_attn(const u16* __restrict__ KT,
                                              const u16* __restrict__ VT,
                                              u16* __restrict__ QB)
{
  __shared__ u16 sK[96 * 72];
  __shared__ u16 sV[64 * 104];
  __shared__ u16 sP[4][32 * 104];

  const int bid = blockIdx.x;
  const int h = bid & 15, b = (bid >> 4) & 15, blk = bid >> 8;
  const int t = threadIdx.x;

  const u16* gK = KT + (size_t)(b * 16 + h) * (96 * 64);
  const u16* gV = VT + (size_t)(b * 16 + h) * (64 * 96);
#pragma unroll
  for (int c = 0; c < 3; ++c) {
    int e = t * 8 + c * 2048;
    { int row = e >> 6, col = e & 63;
      *(u16x8*)&sK[row * 72 + col] = *(const u16x8*)&gK[e]; }
    { int row = e / 96, col = e - (e / 96) * 96;
      *(u16x8*)&sV[row * 104 + col] = *(const u16x8*)&gV[e]; }
  }
  __syncthreads();

  const int l = t & 63, w = t >> 6, lr = l & 15, lg = l >> 4;
  const size_t rowbase = (size_t)b * 4096 + blk * 128 + w * 32;

  bf16x8 aq[2][2];
#pragma unroll
  for (int mt = 0; mt < 2; ++mt)
#pragma unroll
    for (int ks = 0; ks < 2; ++ks)
      aq[mt][ks] = *(const bf16x8*)&QB[(rowbase + mt * 16 + lr) * 1024 + h * 64 + ks * 32 + lg * 8];

  f32x4 s_[2][5] = {};
#pragma unroll
  for (int nt = 0; nt < 5; ++nt) {
#pragma unroll
    for (int ks = 0; ks < 2; ++ks) {
      bf16x8 bk = *(const bf16x8*)&sK[(nt * 16 + lr) * 72 + ks * 32 + lg * 8];
#pragma unroll
      for (int mt = 0; mt < 2; ++mt)
        s_[mt][nt] = __builtin_amdgcn_mfma_f32_16x16x32_bf16(aq[mt][ks], bk, s_[mt][nt], 0, 0, 0);
    }
  }
#pragma unroll
  for (int mt = 0; mt < 2; ++mt)
#pragma unroll
    for (int nt = 0; nt < 5; ++nt)
#pragma unroll
      for (int r = 0; r < 4; ++r)
        s_[mt][nt][r] *= 0.125f;
  if (lr >= 13) {
#pragma unroll
    for (int mt = 0; mt < 2; ++mt)
#pragma unroll
      for (int r = 0; r < 4; ++r)
        s_[mt][4][r] = -1e30f;
  }

  float ri[2][4];
#pragma unroll
  for (int mt = 0; mt < 2; ++mt) {
#pragma unroll
    for (int r = 0; r < 4; ++r) {
      float m1 = s_[mt][0][r];
#pragma unroll
      for (int nt = 1; nt < 5; ++nt) m1 = fmaxf(m1, s_[mt][nt][r]);
      m1 = fmaxf(m1, __shfl_xor(m1, 1, 64));
      m1 = fmaxf(m1, __shfl_xor(m1, 2, 64));
      m1 = fmaxf(m1, __shfl_xor(m1, 4, 64));
      m1 = fmaxf(m1, __shfl_xor(m1, 8, 64));
      float s1 = 0.f;
#pragma unroll
      for (int nt = 0; nt < 5; ++nt) {
        float e = __expf(s_[mt][nt][r] - m1);
        s_[mt][nt][r] = e;
        s1 += e;
      }
      s1 += __shfl_xor(s1, 1, 64);
      s1 += __shfl_xor(s1, 2, 64);
      s1 += __shfl_xor(s1, 4, 64);
      s1 += __shfl_xor(s1, 8, 64);
      ri[mt][r] = 1.0f / s1;
    }
  }

#pragma unroll
  for (int mt = 0; mt < 2; ++mt)
#pragma unroll
    for (int nt = 0; nt < 5; ++nt)
#pragma unroll
      for (int r = 0; r < 4; ++r)
        sP[w][(mt * 16 + lg * 4 + r) * 104 + nt * 16 + lr] = f2bf(s_[mt][nt][r] * ri[mt][r]);
#pragma unroll
  for (int mt = 0; mt < 2; ++mt)
#pragma unroll
    for (int r = 0; r < 4; ++r)
      sP[w][(mt * 16 + lg * 4 + r) * 104 + 80 + lr] = 0;

  f32x4 o_[2][4] = {};
#pragma unroll
  for (int ks = 0; ks < 3; ++ks) {
    bf16x8 ap[2];
#pragma unroll
    for (int mt = 0; mt < 2; ++mt)
      ap[mt] = *(const bf16x8*)&sP[w][(mt * 16 + lr) * 104 + ks * 32 + lg * 8];
#pragma unroll
    for (int nt = 0; nt < 4; ++nt) {
      bf16x8 bv = *(const bf16x8*)&sV[(nt * 16 + lr) * 104 + ks * 32 + lg * 8];
#pragma unroll
      for (int mt = 0; mt < 2; ++mt)
        o_[mt][nt] = __builtin_amdgcn_mfma_f32_16x16x32_bf16(ap[mt], bv, o_[mt][nt], 0, 0, 0);
    }
  }

#pragma unroll
  for (int mt = 0; mt < 2; ++mt)
#pragma unroll
    for (int nt = 0; nt < 4; ++nt)
#pragma unroll
      for (int r = 0; r < 4; ++r)
        QB[(rowbase + mt * 16 + lg * 4 + r) * 1024 + h * 64 + nt * 16 + lr] = f2bf(o_[mt][nt][r]);
}

// ---------------- launch ----------------

extern "C" void kernel_launch(void* const* d_in, const int* in_sizes, int n_in,
                              void* d_out, int out_size, void* d_ws, size_t ws_size,
                              hipStream_t stream) {
  const float* x  = (const float*)d_in[0];
  const float* y  = (const float*)d_in[1];
  const float* wq = (const float*)d_in[2];
  const float* bq = (const float*)d_in[3];
  const float* wk = (const float*)d_in[4];
  const float* bk = (const float*)d_in[5];
  const float* wv = (const float*)d_in[6];
  const float* bv = (const float*)d_in[7];
  const float* wo = (const float*)d_in[8];
  const float* bo = (const float*)d_in[9];

  char* ws = (char*)d_ws;
  u16* QB   = (u16*)(ws + 0);            // 65536x1024 bf16 = 128 MB (Q, then attn out in-place)
  u16* WQ1T = (u16*)(ws + 134217728);    // [1024][1024] bf16, 2 MB
  u16* WO1T = (u16*)(ws + 136314880);    // 2 MB
  u16* WK1T = (u16*)(ws + 138412032);    // [1024][768] bf16, 1.5 MB
  u16* WV1T = (u16*)(ws + 139984896);    // 1.5 MB
  u16* YB   = (u16*)(ws + 141557760);    // [1232][768] bf16, 1.85 MB
  u16* KT   = (u16*)(ws + 143654912);    // [16][16][96][64] bf16, 3 MB
  u16* VT   = (u16*)(ws + 146800640);    // [16][16][64][96] bf16, 3 MB

  u16*   XB  = (u16*)d_out;   // x as bf16, first 128 MB of d_out (consumed before final write)
  float* OUT = (float*)d_out;

  // prep
  k_zero<<<768, 256, 0, stream>>>((u16x8*)KT, 393216);          // zero KT+VT (adjacent, 6 MB)
  k_cvt_x<<<4096, 256, 0, stream>>>(x, XB, 16777216);
  k_prep_w<<<3584, 256, 0, stream>>>(wq, wo, wk, wv, WQ1T, WO1T, WK1T, WV1T);
  k_prep_y<<<924, 256, 0, stream>>>(y, YB, 236544);

  // K+V projections (one launch): M=1232, K=768
  k_gemm_kv<<<160, 256, 0, stream>>>(YB, WK1T, bk, KT, WV1T, bv, VT);

  // Q projection: 256x256 BK=32 triple-buffered GEMM, grid 256 bm x 4 bn
  gemm256<0><<<1024, 512, 0, stream>>>(XB, WQ1T, bq, QB);

  // fused attention, in-place QB -> attn_out
  k_attn<<<8192, 256, 0, stream>>>(KT, VT, QB);

  // output projection -> f32 d_out
  gemm256<1><<<1024, 512, 0, stream>>>(QB, WO1T, bo, OUT);
}